// Round 1
// baseline (149.884 us; speedup 1.0000x reference)
//
#include <hip/hip_runtime.h>
#include <hip/hip_bf16.h>
#include <math.h>

// MMD loss, N=8192 D=128 fp32 in, scalar fp32 out.
// Numerics: reference's (sum(Kxx)-trace) cancels to exactly 0 in fp32; answer =
// -2*S_xy/N^2 (+emulated terms). One bf16-MFMA pass gives approx d2; d2<140 ->
// exact fp32 re-dot; 140..170 -> approx exp; else skip. exp terms scaled e^{+128}.
//
// R5: persistent-block pipeline. R4 counters: MfmaUtil 16.9% but MFMA-busy time
// == dense-peak time for the 34.9 GFLOP => pipe at peak when fed, idle 83%:
// 1 block/CU (130KB LDS) ran {stage 128KB -> drain -> MFMA -> epilogue} serially
// ~8x per CU with dispatch gaps. Now: grid=256 (1 block/CU, ~8 tiles each),
// K=128 split into two 64-halves, double-buffered (2x64KB), T3 2-phase schedule
// with raw s_barrier + vmcnt drains only AFTER an overlapping compute phase.
// Staging of the next half-tile is always in flight under compute/epilogue.
// MFMA order identical to R4 (ks 0..3) -> bitwise-same result.

#define NPTS 8192
#define DDIM 128
#define NTILE 2080   // 528 xx + 528 yy + 1024 xy (256x256 tiles)
#define NBLK 256     // persistent: one block per CU

typedef __bf16 bf16x8 __attribute__((ext_vector_type(8)));
typedef float f32x4 __attribute__((ext_vector_type(4)));

// async 16B global->LDS (direct-to-shared DMA; lane l writes base + l*16)
#define ASYNC_LD16(gp, lp)                                                        \
    __builtin_amdgcn_global_load_lds(                                             \
        (const __attribute__((address_space(1))) unsigned int*)(gp),              \
        (__attribute__((address_space(3))) unsigned int*)(lp), 16, 0, 0)

// raw barriers: do NOT use __syncthreads (it would be fine, but we must control
// exactly where vmcnt drains happen). "memory" clobber pins compiler ordering.
#define BAR_FULL() asm volatile("s_waitcnt vmcnt(0) lgkmcnt(0)\ns_barrier" ::: "memory")
#define BAR_LDS()  asm volatile("s_waitcnt lgkmcnt(0)\ns_barrier" ::: "memory")

// ws layout:
//   0       : double part[2080]
//   16896   : float x2[8192]
//   49664   : float y2[8192]
//   82432   : __bf16 Zb [8192*128]  (2 MB)
//   2179584 : __bf16 Zpb[8192*128]  (2 MB)

__global__ void prep_kernel(const float* __restrict__ Z, const float* __restrict__ Zp,
                            float* __restrict__ x2, float* __restrict__ y2,
                            __bf16* __restrict__ Zb, __bf16* __restrict__ Zpb) {
    const int row = blockIdx.x * 16 + (threadIdx.x >> 4);   // 0..16383
    const int sub = threadIdx.x & 15;
    const float* src; float* nrm; __bf16* dst; int r;
    if (row < NPTS) { src = Z;  nrm = x2; dst = Zb;  r = row; }
    else            { src = Zp; nrm = y2; dst = Zpb; r = row - NPTS; }
    const float4* p = (const float4*)(src + (size_t)r * DDIM) + sub * 2;
    float4 a = p[0], b = p[1];
    float s = a.x*a.x + a.y*a.y + a.z*a.z + a.w*a.w
            + b.x*b.x + b.y*b.y + b.z*b.z + b.w*b.w;
    bf16x8 o = { (__bf16)a.x, (__bf16)a.y, (__bf16)a.z, (__bf16)a.w,
                 (__bf16)b.x, (__bf16)b.y, (__bf16)b.z, (__bf16)b.w };
    *(bf16x8*)(dst + (size_t)r * DDIM + sub * 8) = o;
    #pragma unroll
    for (int off = 8; off; off >>= 1) s += __shfl_down(s, off, 16);
    if (sub == 0) nrm[r] = s;
}

struct TileC { int mat, br, bc; };
__device__ __forceinline__ TileC decode_tile(int t) {
    TileC tc;
    if (t < 1056) {
        tc.mat = (t < 528) ? 0 : 1;
        int idx = t - tc.mat * 528;
        int r = (int)((sqrt(8.0 * (double)idx + 1.0) - 1.0) * 0.5);
        while ((r + 1) * (r + 2) / 2 <= idx) ++r;
        while (r * (r + 1) / 2 > idx) --r;
        tc.br = idx - r * (r + 1) / 2;   // br <= bc: upper triangle
        tc.bc = r;
    } else {
        tc.mat = 2;
        int idx = t - 1056;
        tc.br = idx >> 5; tc.bc = idx & 31;
    }
    return tc;
}

__launch_bounds__(1024, 4)
__global__ void mmd_gemm(const float* __restrict__ Z, const float* __restrict__ Zp,
                         const __bf16* __restrict__ Zb, const __bf16* __restrict__ Zpb,
                         const float* __restrict__ x2g, const float* __restrict__ y2g,
                         double* __restrict__ part) {
    // double-buffered K-halves: [pb][256 rows][64 k] bf16 = 32 KB each side
    __shared__ __bf16 bufA[2][256 * 64];   // 64 KB
    __shared__ __bf16 bufB[2][256 * 64];   // 64 KB
    __shared__ float x2s[256], y2s[256];
    __shared__ float red[16];

    const int tid = threadIdx.x;
    const int w = tid >> 6, lane = tid & 63;
    const int lr = lane & 15, q = lane >> 4;
    const int wm0 = (w >> 2) * 64, wn0 = (w & 3) * 64;

    // ---- stage one K-half (h=0/1) of tile (br,bc) into buffer pb.
    // waves 0-7 -> A-half (32 KB, 4 insts/wave), waves 8-15 -> B-half.
    // LDS[row][c] = G[row][h*64 + (c^(row&7))*8 elems]; 8 chunks/row of 16B,
    // XOR swizzle over 3 bits (row stride 128 B = one full bank cycle).
    // Read side: 16 lanes/col-group -> <=2-way bank alias (free, m136).
    auto stage_half = [&](const __bf16* Xb, const __bf16* Yb, int br, int bc,
                          int h, int pb) {
        const __bf16* src = (w < 8) ? (Xb + (size_t)br * 256 * DDIM)
                                    : (Yb + (size_t)bc * 256 * DDIM);
        char* dst = (char*)((w < 8) ? bufA[pb] : bufB[pb]);
        const int w8 = w & 7;
        #pragma unroll
        for (int i = 0; i < 4; i++) {
            int row = w8 * 32 + i * 8 + (lane >> 3);
            int c = (lane & 7) ^ (row & 7);
            ASYNC_LD16(src + (size_t)row * DDIM + h * 64 + c * 8,
                       dst + w8 * 4096 + i * 1024);
        }
    };

    // ---- MFMA on one resident K-half (2 k32-chunks); 16 waves in 4x4 grid,
    // each 64x64 (4x4 frags of 16x16x32). Same frag geometry as R4.
    auto compute_half = [&](const __bf16* bA, const __bf16* bB, f32x4 (&acc)[4][4]) {
        #pragma unroll
        for (int ks = 0; ks < 2; ks++) {
            const int cx = ((ks * 4 + q) ^ (lr & 7)) * 16;
            bf16x8 a[4], b[4];
            #pragma unroll
            for (int f = 0; f < 4; f++) {
                a[f] = *(const bf16x8*)((const char*)bA + (wm0 + f * 16 + lr) * 128 + cx);
                b[f] = *(const bf16x8*)((const char*)bB + (wn0 + f * 16 + lr) * 128 + cx);
            }
            #pragma unroll
            for (int fm = 0; fm < 4; fm++)
                #pragma unroll
                for (int fn = 0; fn < 4; fn++)
                    acc[fm][fn] = __builtin_amdgcn_mfma_f32_16x16x32_bf16(
                        a[fm], b[fn], acc[fm][fn], 0, 0, 0);
        }
    };

    // ---- prologue: first tile, stage both halves; wait only for h0 (vmcnt(4):
    // each wave issued 4 h0-loads then 4 h1-loads, FIFO).
    int tcur = blockIdx.x;
    TileC tc = decode_tile(tcur);
    {
        const __bf16* XbC = (tc.mat == 1) ? Zpb : Zb;
        const __bf16* YbC = (tc.mat == 0) ? Zb : Zpb;
        stage_half(XbC, YbC, tc.br, tc.bc, 0, 0);
        asm volatile("" ::: "memory");   // pin h0-before-h1 issue order for vmcnt(4)
        stage_half(XbC, YbC, tc.br, tc.bc, 1, 1);
        asm volatile("s_waitcnt vmcnt(4)\ns_barrier" ::: "memory");
    }

    while (true) {
        const float* Xf = (tc.mat == 1) ? Zp : Z;
        const float* Yf = (tc.mat == 0) ? Z : Zp;
        const float* xn = (tc.mat == 1) ? y2g : x2g;
        const float* yn = (tc.mat == 0) ? x2g : y2g;

        const int tnext = tcur + NBLK;
        const bool hasNext = (tnext < NTILE);
        TileC tn = tc;
        const __bf16* XbN = nullptr; const __bf16* YbN = nullptr;
        if (hasNext) {
            tn = decode_tile(tnext);
            XbN = (tn.mat == 1) ? Zpb : Zb;
            YbN = (tn.mat == 0) ? Zb : Zpb;
        }

        f32x4 acc[4][4] = {};

        // phase h0: compute buf0 while buf1 (h1 of cur) is in flight
        compute_half(bufA[0], bufB[0], acc);
        BAR_FULL();                       // buf1 ready; buf0 reads complete everywhere
        if (hasNext) stage_half(XbN, YbN, tn.br, tn.bc, 0, 0);
        if (tid < 256)      x2s[tid]       = xn[tc.br * 256 + tid];
        else if (tid < 512) y2s[tid - 256] = yn[tc.bc * 256 + (tid - 256)];

        // phase h1: compute buf1 while buf0 (h0 of next) is in flight
        compute_half(bufA[1], bufB[1], acc);
        BAR_FULL();                       // buf0 ready; buf1 free; norms visible
        if (hasNext) stage_half(XbN, YbN, tn.br, tn.bc, 1, 1);

        // ---- epilogue (overlaps the h1-of-next staging): same math as R4.
        // C/D layout: col = lane&15, row = (lane>>4)*4 + reg  [m89/m91]
        const bool isDiag = (tc.mat < 2) && (tc.br == tc.bc);
        float t170[4], syv[4];
        #pragma unroll
        for (int fn = 0; fn < 4; fn++) {
            float s = y2s[wn0 + fn * 16 + lr];
            syv[fn] = s; t170[fn] = 170.f - s;
        }

        float accS = 0.f;
        #pragma unroll
        for (int fm = 0; fm < 4; fm++) {
            const float4 xv = *(const float4*)&x2s[wm0 + fm * 16 + q * 4];
            #pragma unroll
            for (int r = 0; r < 4; r++) {
                const float xvr = (r == 0) ? xv.x : (r == 1) ? xv.y : (r == 2) ? xv.z : xv.w;
                const int ci = wm0 + fm * 16 + q * 4 + r;
                #pragma unroll
                for (int fn = 0; fn < 4; fn++) {
                    float lhs = fmaf(-2.f, acc[fm][fn][r], xvr);
                    if (lhs < t170[fn]) {
                        const int cj = wn0 + fn * 16 + lr;
                        if (isDiag && ci == cj) continue;    // trace excluded
                        float d2 = lhs + syv[fn];
                        float term;
                        if (d2 < 140.f) {
                            // exact fp32 re-dot (rare)
                            const int gi = tc.br * 256 + ci, gj = tc.bc * 256 + cj;
                            const float4* xr = (const float4*)(Xf + (size_t)gi * DDIM);
                            const float4* yr = (const float4*)(Yf + (size_t)gj * DDIM);
                            float dot = 0.f;
                            #pragma unroll 8
                            for (int k = 0; k < 32; k++) {
                                float4 xa = xr[k], yb = yr[k];
                                dot += xa.x * yb.x + xa.y * yb.y + xa.z * yb.z + xa.w * yb.w;
                            }
                            float d2e = fmaxf(xvr + syv[fn] - 2.f * dot, 0.f);
                            term = __expf(fminf(128.f - 0.5f * d2e, 85.f));
                        } else {
                            term = __expf(128.f - 0.5f * d2);
                        }
                        accS += term;
                    }
                }
            }
        }

        // reduce: fp32 wave shfl -> LDS -> one store per tile (no atomics).
        // BAR_LDS only: do NOT drain vmcnt (h1-of-next staging stays in flight).
        #pragma unroll
        for (int off = 32; off; off >>= 1) accS += __shfl_down(accS, off);
        if (lane == 0) red[w] = accS;
        BAR_LDS();
        if (tid == 0) {
            double tot = 0.0;
            #pragma unroll
            for (int i = 0; i < 16; i++) tot += (double)red[i];
            double wgt = (tc.mat < 2 && tc.br != tc.bc) ? 2.0 : 1.0;
            part[tcur] = tot * wgt;
        }

        if (!hasNext) break;
        tcur = tnext; tc = tn;
    }
}

__global__ void finalize_kernel(const double* __restrict__ part, float* __restrict__ out) {
    __shared__ double red[3][4];
    const int tid = threadIdx.x, w = tid >> 6, lane = tid & 63;
    double sxx = 0.0, syy = 0.0, sxy = 0.0;
    for (int i = tid; i < 528; i += 256)          sxx += part[i];
    for (int i = 528 + tid; i < 1056; i += 256)   syy += part[i];
    for (int i = 1056 + tid; i < NTILE; i += 256) sxy += part[i];
    #pragma unroll
    for (int off = 32; off; off >>= 1) {
        sxx += __shfl_down(sxx, off);
        syy += __shfl_down(syy, off);
        sxy += __shfl_down(sxy, off);
    }
    if (lane == 0) { red[0][w] = sxx; red[1][w] = syy; red[2][w] = sxy; }
    __syncthreads();
    if (tid == 0) {
        const double EM = exp(-128.0);
        double Sxx = (red[0][0] + red[0][1] + red[0][2] + red[0][3]) * EM;
        double Syy = (red[1][0] + red[1][1] + red[1][2] + red[1][3]) * EM;
        double Sxy = (red[2][0] + red[2][1] + red[2][2] + red[2][3]) * EM;
        float sumxx = (float)(8192.0 + Sxx);
        float sumyy = (float)(8192.0 + Syy);
        const float scale = 8191.0f / 8192.0f;
        float kxx = (sumxx - 8192.0f) * scale;
        float kyy = (sumyy - 8192.0f) * scale;
        float kxy = (float)(Sxy / (8192.0 * 8192.0));
        out[0] = kxx + kyy - 2.0f * kxy;
    }
}

extern "C" void kernel_launch(void* const* d_in, const int* in_sizes, int n_in,
                              void* d_out, int out_size, void* d_ws, size_t ws_size,
                              hipStream_t stream) {
    const float* z  = (const float*)d_in[0];
    const float* zp = (const float*)d_in[1];
    double* part = (double*)d_ws;                         // 2080 doubles
    float* x2 = (float*)((char*)d_ws + 16896);
    float* y2 = (float*)((char*)d_ws + 49664);
    __bf16* Zb  = (__bf16*)((char*)d_ws + 82432);
    __bf16* Zpb = (__bf16*)((char*)d_ws + 2179584);

    prep_kernel<<<1024, 256, 0, stream>>>(z, zp, x2, y2, Zb, Zpb);
    mmd_gemm<<<NBLK, 1024, 0, stream>>>(z, zp, Zb, Zpb, x2, y2, part);
    finalize_kernel<<<1, 256, 0, stream>>>(part, (float*)d_out);
}

// Round 3
// 129.802 us; speedup vs baseline: 1.1547x; 1.1547x over previous
//
#include <hip/hip_runtime.h>
#include <hip/hip_bf16.h>
#include <math.h>

// MMD loss, N=8192 D=128 fp32 in, scalar fp32 out.
// Numerics: reference's (sum(Kxx)-trace) cancels to exactly 0 in fp32; answer =
// -2*S_xy/N^2 (+emulated terms). One bf16-MFMA pass gives approx d2; d2<140 ->
// exact fp32 re-dot; 140..170 -> approx exp; else skip. exp terms scaled e^{+128}.
//
// R6 (resubmit after infra failure): proven m97 occupancy model. R5 post-mortem:
// persistent 1024-thr blocks still occupy a full CU (130KB LDS) -> 1 block/CU,
// so every vmcnt(0) drain at a barrier idles ALL resident waves; manual
// pipelining at HIP source lost to the drain (m99/m131-m141 lesson). Fix via
// TLP not scheduling: 128x128 tiles, 256-thr blocks (4 waves, 2x2 of 64x64),
// BK=64 single-buffered LDS = 33 KB, 128 unified regs -> 4 independent
// blocks/CU. One block's stage+drain overlaps the other three blocks'
// MFMA/epilogue (m114). Per-wave MFMA/LDS intensity identical to R4/R5;
// epilogue math bit-identical.

#define NPTS 8192
#define DDIM 128
#define TRI  2080     // 64*65/2 triangle tiles per symmetric matrix
#define NTILE 8256    // 2080 xx + 2080 yy + 4096 xy (128x128 tiles)

typedef __bf16 bf16x8 __attribute__((ext_vector_type(8)));
typedef float f32x4 __attribute__((ext_vector_type(4)));

// async 16B global->LDS (direct-to-shared DMA; lane l writes base + l*16)
#define ASYNC_LD16(gp, lp)                                                        \
    __builtin_amdgcn_global_load_lds(                                             \
        (const __attribute__((address_space(1))) unsigned int*)(gp),              \
        (__attribute__((address_space(3))) unsigned int*)(lp), 16, 0, 0)

// ws layout:
//   0       : double part[8256]          (66048 B, scaled e^{+128})
//   66048   : float x2[8192]
//   98816   : float y2[8192]
//   131584  : __bf16 Zb [8192*128]  (2 MB)
//   2228736 : __bf16 Zpb[8192*128]  (2 MB)   total ~4.33 MB

__global__ void prep_kernel(const float* __restrict__ Z, const float* __restrict__ Zp,
                            float* __restrict__ x2, float* __restrict__ y2,
                            __bf16* __restrict__ Zb, __bf16* __restrict__ Zpb) {
    const int row = blockIdx.x * 16 + (threadIdx.x >> 4);   // 0..16383
    const int sub = threadIdx.x & 15;
    const float* src; float* nrm; __bf16* dst; int r;
    if (row < NPTS) { src = Z;  nrm = x2; dst = Zb;  r = row; }
    else            { src = Zp; nrm = y2; dst = Zpb; r = row - NPTS; }
    const float4* p = (const float4*)(src + (size_t)r * DDIM) + sub * 2;
    float4 a = p[0], b = p[1];
    float s = a.x*a.x + a.y*a.y + a.z*a.z + a.w*a.w
            + b.x*b.x + b.y*b.y + b.z*b.z + b.w*b.w;
    bf16x8 o = { (__bf16)a.x, (__bf16)a.y, (__bf16)a.z, (__bf16)a.w,
                 (__bf16)b.x, (__bf16)b.y, (__bf16)b.z, (__bf16)b.w };
    *(bf16x8*)(dst + (size_t)r * DDIM + sub * 8) = o;
    #pragma unroll
    for (int off = 8; off; off >>= 1) s += __shfl_down(s, off, 16);
    if (sub == 0) nrm[r] = s;
}

struct TileC { int mat, br, bc; };
__device__ __forceinline__ TileC decode_tile(int t) {
    TileC tc;
    if (t < 2 * TRI) {
        tc.mat = (t < TRI) ? 0 : 1;
        int idx = t - tc.mat * TRI;
        int r = (int)((sqrt(8.0 * (double)idx + 1.0) - 1.0) * 0.5);
        while ((r + 1) * (r + 2) / 2 <= idx) ++r;
        while (r * (r + 1) / 2 > idx) --r;
        tc.br = idx - r * (r + 1) / 2;   // br <= bc: upper triangle
        tc.bc = r;
    } else {
        tc.mat = 2;
        int idx = t - 2 * TRI;
        tc.br = idx >> 6; tc.bc = idx & 63;
    }
    return tc;
}

__launch_bounds__(256, 4)
__global__ void mmd_gemm(const float* __restrict__ Z, const float* __restrict__ Zp,
                         const __bf16* __restrict__ Zb, const __bf16* __restrict__ Zpb,
                         const float* __restrict__ x2g, const float* __restrict__ y2g,
                         double* __restrict__ part) {
    __shared__ __bf16 As[128 * 64];   // 16 KB, 128-B rows, XOR-swizzled 16B chunks
    __shared__ __bf16 Bs[128 * 64];   // 16 KB
    __shared__ float x2s[128], y2s[128];
    __shared__ float red[4];

    const int tid = threadIdx.x;
    const int w = tid >> 6, lane = tid & 63;
    const int lr = lane & 15, q = lane >> 4;
    const int wm0 = (w >> 1) * 64, wn0 = (w & 1) * 64;

    TileC tc = decode_tile(blockIdx.x);
    const float*  Xf = (tc.mat == 1) ? Zp  : Z;
    const float*  Yf = (tc.mat == 0) ? Z   : Zp;
    const __bf16* Xb = (tc.mat == 1) ? Zpb : Zb;
    const __bf16* Yb = (tc.mat == 0) ? Zb  : Zpb;
    const float*  xn = (tc.mat == 1) ? y2g : x2g;
    const float*  yn = (tc.mat == 0) ? x2g : y2g;

    // ---- stage one K-half h (64 wide): waves 0,1 -> A rows 0-63 / 64-127,
    // waves 2,3 -> B. Per wave 8 insts x 1 KB. LDS[row][c] = G[row][h*64 +
    // (c^(row&7))*8 elems] — same swizzle geometry as R4/R5 (0 bank conflicts).
    auto stage = [&](int h) {
        const __bf16* src = (w < 2) ? (Xb + (size_t)tc.br * 128 * DDIM)
                                    : (Yb + (size_t)tc.bc * 128 * DDIM);
        char* dst = (char*)((w < 2) ? As : Bs) + (w & 1) * 8192;
        #pragma unroll
        for (int t = 0; t < 8; t++) {
            int row = (w & 1) * 64 + t * 8 + (lane >> 3);
            int c = (lane & 7) ^ (row & 7);
            ASYNC_LD16(src + (size_t)row * DDIM + h * 64 + c * 8, dst + t * 1024);
        }
    };

    f32x4 acc[4][4] = {};
    // ---- one K-half of MFMAs: 2 k32-chunks, 4x4 frags of 16x16x32 per wave
    auto compute = [&]() {
        #pragma unroll
        for (int ks = 0; ks < 2; ks++) {
            const int cx = ((ks * 4 + q) ^ (lr & 7)) * 16;
            bf16x8 a[4], b[4];
            #pragma unroll
            for (int f = 0; f < 4; f++) {
                a[f] = *(const bf16x8*)((const char*)As + (wm0 + f * 16 + lr) * 128 + cx);
                b[f] = *(const bf16x8*)((const char*)Bs + (wn0 + f * 16 + lr) * 128 + cx);
            }
            #pragma unroll
            for (int fm = 0; fm < 4; fm++)
                #pragma unroll
                for (int fn = 0; fn < 4; fn++)
                    acc[fm][fn] = __builtin_amdgcn_mfma_f32_16x16x32_bf16(
                        a[fm], b[fn], acc[fm][fn], 0, 0, 0);
        }
    };

    stage(0);
    if (tid < 128) x2s[tid]       = xn[tc.br * 128 + tid];
    else           y2s[tid - 128] = yn[tc.bc * 128 + (tid - 128)];
    __syncthreads();
    compute();
    __syncthreads();          // all reads of h0 done before overwrite
    stage(1);
    __syncthreads();
    compute();

    // ---- epilogue: fast path per elem = 1 fma + 1 cmp (threshold folded)
    // C/D layout: col = lane&15, row = (lane>>4)*4 + reg  [m89/m91]
    const bool isDiag = (tc.mat < 2) && (tc.br == tc.bc);
    float t170[4], syv[4];
    #pragma unroll
    for (int fn = 0; fn < 4; fn++) {
        float s = y2s[wn0 + fn * 16 + lr];
        syv[fn] = s; t170[fn] = 170.f - s;
    }

    float accS = 0.f;
    #pragma unroll
    for (int fm = 0; fm < 4; fm++) {
        const float4 xv = *(const float4*)&x2s[wm0 + fm * 16 + q * 4]; // rows q*4..+3
        #pragma unroll
        for (int r = 0; r < 4; r++) {
            const float xvr = (r == 0) ? xv.x : (r == 1) ? xv.y : (r == 2) ? xv.z : xv.w;
            const int ci = wm0 + fm * 16 + q * 4 + r;
            #pragma unroll
            for (int fn = 0; fn < 4; fn++) {
                float lhs = fmaf(-2.f, acc[fm][fn][r], xvr);
                if (lhs < t170[fn]) {
                    const int cj = wn0 + fn * 16 + lr;
                    if (isDiag && ci == cj) continue;    // diagonal excluded (trace)
                    float d2 = lhs + syv[fn];
                    float term;
                    if (d2 < 140.f) {
                        // exact fp32 re-dot (rare)
                        const int gi = tc.br * 128 + ci, gj = tc.bc * 128 + cj;
                        const float4* xr = (const float4*)(Xf + (size_t)gi * DDIM);
                        const float4* yr = (const float4*)(Yf + (size_t)gj * DDIM);
                        float dot = 0.f;
                        #pragma unroll 8
                        for (int k = 0; k < 32; k++) {
                            float4 xa = xr[k], yb = yr[k];
                            dot += xa.x * yb.x + xa.y * yb.y + xa.z * yb.z + xa.w * yb.w;
                        }
                        float d2e = fmaxf(xvr + syv[fn] - 2.f * dot, 0.f);
                        term = __expf(fminf(128.f - 0.5f * d2e, 85.f)); // clamp: no inf
                    } else {
                        term = __expf(128.f - 0.5f * d2);
                    }
                    accS += term;
                }
            }
        }
    }

    // ---- reduce: fp32 wave shfl -> LDS -> ONE plain store per block (no atomics)
    #pragma unroll
    for (int off = 32; off; off >>= 1) accS += __shfl_down(accS, off);
    if (lane == 0) red[w] = accS;
    __syncthreads();
    if (tid == 0) {
        double tot = (double)red[0] + (double)red[1] + (double)red[2] + (double)red[3];
        double wgt = (tc.mat < 2 && tc.br != tc.bc) ? 2.0 : 1.0;  // mirror off-diag
        part[blockIdx.x] = tot * wgt;
    }
}

__global__ void finalize_kernel(const double* __restrict__ part, float* __restrict__ out) {
    __shared__ double red[3][4];
    const int tid = threadIdx.x, w = tid >> 6, lane = tid & 63;
    double sxx = 0.0, syy = 0.0, sxy = 0.0;
    for (int i = tid; i < TRI; i += 256)                sxx += part[i];
    for (int i = TRI + tid; i < 2 * TRI; i += 256)      syy += part[i];
    for (int i = 2 * TRI + tid; i < NTILE; i += 256)    sxy += part[i];
    #pragma unroll
    for (int off = 32; off; off >>= 1) {
        sxx += __shfl_down(sxx, off);
        syy += __shfl_down(syy, off);
        sxy += __shfl_down(sxy, off);
    }
    if (lane == 0) { red[0][w] = sxx; red[1][w] = syy; red[2][w] = sxy; }
    __syncthreads();
    if (tid == 0) {
        const double EM = exp(-128.0);
        double Sxx = (red[0][0] + red[0][1] + red[0][2] + red[0][3]) * EM;
        double Syy = (red[1][0] + red[1][1] + red[1][2] + red[1][3]) * EM;
        double Sxy = (red[2][0] + red[2][1] + red[2][2] + red[2][3]) * EM;
        // Emulate reference fp32 absorption: fl32(N + S_off) - N
        float sumxx = (float)(8192.0 + Sxx);
        float sumyy = (float)(8192.0 + Syy);
        const float scale = 8191.0f / 8192.0f;
        float kxx = (sumxx - 8192.0f) * scale;
        float kyy = (sumyy - 8192.0f) * scale;
        float kxy = (float)(Sxy / (8192.0 * 8192.0));
        out[0] = kxx + kyy - 2.0f * kxy;
    }
}

extern "C" void kernel_launch(void* const* d_in, const int* in_sizes, int n_in,
                              void* d_out, int out_size, void* d_ws, size_t ws_size,
                              hipStream_t stream) {
    const float* z  = (const float*)d_in[0];
    const float* zp = (const float*)d_in[1];
    double* part = (double*)d_ws;                         // 8256 doubles
    float* x2 = (float*)((char*)d_ws + 66048);
    float* y2 = (float*)((char*)d_ws + 98816);
    __bf16* Zb  = (__bf16*)((char*)d_ws + 131584);
    __bf16* Zpb = (__bf16*)((char*)d_ws + 2228736);

    prep_kernel<<<1024, 256, 0, stream>>>(z, zp, x2, y2, Zb, Zpb);
    mmd_gemm<<<NTILE, 256, 0, stream>>>(z, zp, Zb, Zpb, x2, y2, part);
    finalize_kernel<<<1, 256, 0, stream>>>(part, (float*)d_out);
}